// Round 9
// baseline (223.369 us; speedup 1.0000x reference)
//
#include <hip/hip_runtime.h>
#include <hip/hip_fp16.h>
#include <cstddef>
#include <cstdint>

static constexpr int NN   = 50000;   // nodes
static constexpr int NE   = 800000;  // edges (without self loops)
static constexpr int NG   = 256;     // graphs
static constexpr int FIN  = 128;
static constexpr int HID  = 256;
static constexpr int EMB  = 128;
static constexpr int NGRP = 16;
static constexpr int NFAM = 128;
static constexpr int NETOT = NE + NN;  // edges + self loops

static constexpr int SCAN_B  = 256;
static constexpr int SCAN_CH = (NN + SCAN_B - 1) / SCAN_B;  // 196

static constexpr int NSLICE  = 8;                            // XCD slices
static constexpr int SLICE_W = (NN + NSLICE - 1) / NSLICE;   // 6250 nodes
static constexpr int BUILD_RANKS = 64;                       // blocks per slice

using bf16x8 = __attribute__((ext_vector_type(8))) short;
using f32x4  = __attribute__((ext_vector_type(4))) float;

__device__ __forceinline__ unsigned short f2bf(float f) {
    uint32_t u = __float_as_uint(f);
    u += 0x7FFFu + ((u >> 16) & 1u);
    return (unsigned short)(u >> 16);
}
__device__ __forceinline__ float bf2f(unsigned short u) {
    return __uint_as_float((uint32_t)u << 16);
}
// packed edge: low16 = src node, high16 = fp16 weight
__device__ __forceinline__ uint32_t pack_sw(int s, float w) {
    return (uint32_t)s | ((uint32_t)__half_as_ushort(__float2half(w)) << 16);
}
__device__ __forceinline__ void unpack_sw(uint32_t v, int& s, float& w) {
    s = (int)(v & 0xFFFFu);
    w = __half2float(__ushort_as_half((unsigned short)(v >> 16)));
}

// ---------------- setup ----------------
// degi starts at 0 (memsetAsync); true degree = degi + 1 (self loop).

__global__ void k_count(const int* __restrict__ edst, int* __restrict__ degi, int e) {
    int i = blockIdx.x * blockDim.x + threadIdx.x;
    if (i < e) atomicAdd(degi + edst[i], 1);
}

// dinv + gstart + zero(emb_acc)
__global__ void k_prep(const int* __restrict__ degi, const int* __restrict__ batch,
                       float* __restrict__ dinv, int* __restrict__ gstart,
                       float* __restrict__ emb_acc, int n, int G) {
    int i = blockIdx.x * blockDim.x + threadIdx.x;   // 0..65535
    if (i < NG * EMB) emb_acc[i] = 0.f;
    if (i >= n) return;
    dinv[i] = rsqrtf((float)(degi[i] + 1));
    int b  = batch[i];
    int pb = (i == 0) ? -1 : batch[i - 1];
    for (int g = pb + 1; g <= b; ++g) gstart[g] = i;
    if (i == n - 1) {
        for (int g = b + 1; g <= G; ++g) gstart[g] = n;
    }
}

// xs = bf16(dinv[node] * x), vectorized 8/thread
__global__ void k_xconv(const float* __restrict__ x, const float* __restrict__ dinv,
                        unsigned short* __restrict__ xs) {
    int t = blockIdx.x * blockDim.x + threadIdx.x;   // NN*16 threads
    size_t i = (size_t)t * 8;
    float dv = dinv[t >> 4];
    float4 a = *(const float4*)(x + i);
    float4 b = *(const float4*)(x + i + 4);
    uint4 o;
    o.x = (uint32_t)f2bf(dv * a.x) | ((uint32_t)f2bf(dv * a.y) << 16);
    o.y = (uint32_t)f2bf(dv * a.z) | ((uint32_t)f2bf(dv * a.w) << 16);
    o.z = (uint32_t)f2bf(dv * b.x) | ((uint32_t)f2bf(dv * b.y) << 16);
    o.w = (uint32_t)f2bf(dv * b.z) | ((uint32_t)f2bf(dv * b.w) << 16);
    *(uint4*)(xs + i) = o;
}

// W1 [128][256] -> W1t [256][128] bf16 ; W2 [256][128] -> W2t [128][256] bf16
__global__ void k_wconv(const float* __restrict__ W1, const float* __restrict__ W2,
                        unsigned short* __restrict__ W1t, unsigned short* __restrict__ W2t) {
    int t = blockIdx.x * blockDim.x + threadIdx.x;  // 0..65535
    if (t < HID * FIN) {
        int nidx = t >> 7, k = t & 127;
        W1t[t] = f2bf(W1[(size_t)k * HID + nidx]);
    } else {
        int u = t - HID * FIN;
        int nidx = u >> 8, k = u & 255;
        W2t[u] = f2bf(W2[(size_t)k * EMB + nidx]);
    }
}

// ---------------- parallel scan (2 kernels); counts are degi[i]+1 ----------------

__global__ __launch_bounds__(256) void k_scanA(const int* __restrict__ degi,
                                               int* __restrict__ row_ptr,
                                               int* __restrict__ bsum, int n) {
    __shared__ int sh[256];
    const int b = blockIdx.x, t = threadIdx.x;
    const int idx = b * SCAN_CH + t;
    int v = 0;
    if (t < SCAN_CH && idx < n) v = degi[idx] + 1;
    sh[t] = v;
    __syncthreads();
    for (int off = 1; off < 256; off <<= 1) {
        int y = (t >= off) ? sh[t - off] : 0;
        __syncthreads();
        if (t >= off) sh[t] += y;
        __syncthreads();
    }
    if (t < SCAN_CH && idx < n) row_ptr[idx] = sh[t] - v;  // exclusive
    if (t == 255) bsum[b] = sh[255];
}

__global__ __launch_bounds__(256) void k_scanB(const int* __restrict__ bsum,
                                               const int* __restrict__ gstart,
                                               float* __restrict__ rcnt,
                                               int* __restrict__ row_ptr,
                                               int* __restrict__ cursor, int n) {
    __shared__ int sh[SCAN_B];
    const int b = blockIdx.x, t = threadIdx.x;
    sh[t] = bsum[t];
    __syncthreads();
    for (int off = 1; off < SCAN_B; off <<= 1) {
        int y = (t >= off) ? sh[t - off] : 0;
        __syncthreads();
        if (t >= off) sh[t] += y;
        __syncthreads();
    }
    const int boff = (b == 0) ? 0 : sh[b - 1];
    const int idx  = b * SCAN_CH + t;
    if (t < SCAN_CH && idx < n) {
        row_ptr[idx] += boff;
        cursor[idx] = 1;   // slot 0 = self loop
    }
    if (b == 0 && t == 0) row_ptr[n] = sh[SCAN_B - 1];
    if (b == 0 && t < NG) {
        int c = gstart[t + 1] - gstart[t];
        rcnt[t] = 1.0f / (float)max(c, 1);
    }
}

// ---------------- XCD-sliced CSR fill ----------------
// slice = blk&7 owns dst in [slice*SLICE_W, ...): its eP range stays in one
// XCD's L2 (blocks round-robin over XCDs), so scatter lines stop ping-ponging.
// Each slice re-reads the full edst stream (cheap, streaming).

__global__ __launch_bounds__(256) void k_build(
        const int* __restrict__ esrc, const int* __restrict__ edst,
        const int* __restrict__ batch, const float* __restrict__ dinv,
        const float* __restrict__ rcnt, const int* __restrict__ row_ptr,
        int* __restrict__ cursor, uint32_t* __restrict__ eP, int n, int e) {
    const int slice = blockIdx.x & 7;
    const int rank  = blockIdx.x >> 3;
    const int lo = slice * SLICE_W;
    const int hi = min(lo + SLICE_W, n);
    // self loops (coalesced within slice range)
    for (int i = lo + rank * 256 + (int)threadIdx.x; i < hi; i += BUILD_RANKS * 256) {
        eP[row_ptr[i]] = pack_sw(i, dinv[i] * rcnt[batch[i]]);
    }
    // edges: filter by dst slice
    for (int j = rank * 256 + (int)threadIdx.x; j < e; j += BUILD_RANKS * 256) {
        int d = edst[j];
        if (d < lo || d >= hi) continue;
        int s = esrc[j];
        int p = atomicAdd(cursor + d, 1);
        eP[row_ptr[d] + p] = pack_sw(s, dinv[d] * rcnt[batch[d]]);
    }
}

// ---------------- layer-1 gather: xa[i] = bf16(dinv_i * sum_j xs[src_j]) ----
// 4 edges per wave-load: grp = lane>>4 edge slot, fl = lane&15 (16 B features).

__global__ __launch_bounds__(256) void k_agg(
        const unsigned short* __restrict__ xs, const int* __restrict__ row_ptr,
        const uint32_t* __restrict__ eP, const float* __restrict__ dinv,
        unsigned short* __restrict__ xa, int n) {
    int node = blockIdx.x * 4 + (threadIdx.x >> 6);
    if (node >= n) return;
    int lane = threadIdx.x & 63;
    int grp = lane >> 4, fl = lane & 15;
    float acc[8] = {};
    int beg = row_ptr[node], end = row_ptr[node + 1];
    for (int j = beg; j < end; j += 4) {
        int jj = j + grp;
        bool valid = jj < end;
        uint32_t ev = __builtin_nontemporal_load(eP + (valid ? jj : beg));
        int s = (int)(ev & 0xFFFFu);
        float m = valid ? 1.f : 0.f;
        bf16x8 v = *(const bf16x8*)(xs + ((size_t)s << 7) + fl * 8);
#pragma unroll
        for (int k = 0; k < 8; ++k)
            acc[k] += m * bf2f((unsigned short)v[k]);
    }
#pragma unroll
    for (int k = 0; k < 8; ++k) {
        acc[k] += __shfl_xor(acc[k], 16);
        acc[k] += __shfl_xor(acc[k], 32);
    }
    if (lane < 16) {
        float di = dinv[node];
        uint4 o;
        o.x = (uint32_t)f2bf(di * acc[0]) | ((uint32_t)f2bf(di * acc[1]) << 16);
        o.y = (uint32_t)f2bf(di * acc[2]) | ((uint32_t)f2bf(di * acc[3]) << 16);
        o.z = (uint32_t)f2bf(di * acc[4]) | ((uint32_t)f2bf(di * acc[5]) << 16);
        o.w = (uint32_t)f2bf(di * acc[6]) | ((uint32_t)f2bf(di * acc[7]) << 16);
        *(uint4*)(xa + ((size_t)node << 7) + fl * 8) = o;
    }
}

// ---------------- fused GEMM: H = bf16( dinv_row * relu(xa@W1+b1) @ W2 ) ----

__global__ __launch_bounds__(256) void k_fgemm(
        const unsigned short* __restrict__ A,   // xa [M][128]
        const unsigned short* __restrict__ W1t, // [256][128]
        const unsigned short* __restrict__ W2t, // [128][256]
        const float* __restrict__ b1, const float* __restrict__ dinv,
        unsigned short* __restrict__ H, int M) {
    __shared__ unsigned short h1s[64 * 256];  // 32 KB
    const int m0 = blockIdx.x * 64;
    const int w  = threadIdx.x >> 6;
    const int l  = threadIdx.x & 63;
    const int lr = l & 15;
    const int lk = l >> 4;  // 0..3

    // stage 1: cols w*64 .. w*64+63
    {
        f32x4 acc[4][4] = {};
        const int n0 = w * 64;
#pragma unroll
        for (int ks = 0; ks < 4; ++ks) {
            const int k0 = ks * 32 + lk * 8;
            bf16x8 bfr[4];
#pragma unroll
            for (int ni = 0; ni < 4; ++ni)
                bfr[ni] = *(const bf16x8*)(W1t + (size_t)(n0 + ni * 16 + lr) * FIN + k0);
#pragma unroll
            for (int mi = 0; mi < 4; ++mi) {
                int row = min(m0 + mi * 16 + lr, M - 1);
                bf16x8 afr = *(const bf16x8*)(A + ((size_t)row << 7) + k0);
#pragma unroll
                for (int ni = 0; ni < 4; ++ni)
                    acc[mi][ni] = __builtin_amdgcn_mfma_f32_16x16x32_bf16(
                        afr, bfr[ni], acc[mi][ni], 0, 0, 0);
            }
        }
#pragma unroll
        for (int ni = 0; ni < 4; ++ni) {
            int col = n0 + ni * 16 + lr;
            float bb = b1[col];
#pragma unroll
            for (int mi = 0; mi < 4; ++mi) {
#pragma unroll
                for (int r = 0; r < 4; ++r) {
                    int rl = mi * 16 + lk * 4 + r;
                    float dv = dinv[min(m0 + rl, M - 1)];
                    float v = fmaxf(acc[mi][ni][r] + bb, 0.f) * dv;
                    int byte = (rl * 512 + col * 2) ^ ((rl & 7) << 4);
                    *(unsigned short*)((char*)h1s + byte) = f2bf(v);
                }
            }
        }
    }
    __syncthreads();
    // stage 2: cols w*32 .. w*32+31, K=256 from LDS
    f32x4 acc2[4][2] = {};
    {
        const int n0 = w * 32;
#pragma unroll
        for (int ks = 0; ks < 8; ++ks) {
            const int k0 = ks * 32 + lk * 8;
            bf16x8 bfr[2];
#pragma unroll
            for (int ni = 0; ni < 2; ++ni)
                bfr[ni] = *(const bf16x8*)(W2t + (size_t)(n0 + ni * 16 + lr) * HID + k0);
#pragma unroll
            for (int mi = 0; mi < 4; ++mi) {
                int rl = mi * 16 + lr;
                int byte = (rl * 512 + k0 * 2) ^ ((rl & 7) << 4);
                bf16x8 afr = *(const bf16x8*)((const char*)h1s + byte);
#pragma unroll
                for (int ni = 0; ni < 2; ++ni)
                    acc2[mi][ni] = __builtin_amdgcn_mfma_f32_16x16x32_bf16(
                        afr, bfr[ni], acc2[mi][ni], 0, 0, 0);
            }
        }
    }
    __syncthreads();  // all LDS reads done before reuse
    {
        const int n0 = w * 32;
#pragma unroll
        for (int ni = 0; ni < 2; ++ni) {
            int col = n0 + ni * 16 + lr;
#pragma unroll
            for (int mi = 0; mi < 4; ++mi)
#pragma unroll
                for (int r = 0; r < 4; ++r) {
                    int rl = mi * 16 + lk * 4 + r;
                    h1s[rl * EMB + col] = f2bf(acc2[mi][ni][r]);
                }
        }
    }
    __syncthreads();
    // coalesced store: rows m0..m0+nrows, 128 bf16 each (16 x 16B chunks)
    int nrows = min(64, M - m0);
    for (int c = threadIdx.x; c < nrows * 16; c += 256) {
        int rl = c >> 4, cc = c & 15;
        *(uint4*)(H + ((size_t)(m0 + rl) << 7) + cc * 8) =
            *(const uint4*)(h1s + rl * EMB + cc * 8);
    }
}

// ---------------- pool: emb_acc[g] += sum_e w_e * H[src_e]  (128 feats) ----

__global__ __launch_bounds__(256) void k_pool(
        const unsigned short* __restrict__ H, const int* __restrict__ row_ptr,
        const int* __restrict__ gstart, const uint32_t* __restrict__ eP,
        float* __restrict__ emb_acc) {
    __shared__ float red[4][EMB];
    const int g  = blockIdx.x >> 3;
    const int kb = blockIdx.x & 7;
    const int e0 = row_ptr[gstart[g]];
    const int e1 = row_ptr[gstart[g + 1]];
    const int len = e1 - e0;
    const int per = (len + 7) >> 3;
    const int s0  = e0 + kb * per;
    const int s1  = min(s0 + per, e1);
    const int lane = threadIdx.x & 63;
    const int wv   = threadIdx.x >> 6;
    const int grp = lane >> 4, fl = lane & 15;

    float acc[8] = {};
    for (int j = s0 + wv * 4; j < s1; j += 16) {
        int jj = j + grp;
        bool valid = jj < s1;
        uint32_t ev = __builtin_nontemporal_load(eP + (valid ? jj : s0));
        int s; float wgt;
        unpack_sw(ev, s, wgt);
        if (!valid) wgt = 0.f;
        bf16x8 v = *(const bf16x8*)(H + ((size_t)s << 7) + fl * 8);
#pragma unroll
        for (int k = 0; k < 8; ++k)
            acc[k] += wgt * bf2f((unsigned short)v[k]);
    }
#pragma unroll
    for (int k = 0; k < 8; ++k) {
        acc[k] += __shfl_xor(acc[k], 16);
        acc[k] += __shfl_xor(acc[k], 32);
    }
    if (lane < 16) {
#pragma unroll
        for (int k = 0; k < 8; ++k) red[wv][fl * 8 + k] = acc[k];
    }
    __syncthreads();
    int t = threadIdx.x;
    if (t < EMB) {
        float v = red[0][t] + red[1][t] + red[2][t] + red[3][t];
        if (v != 0.f) atomicAdd(&emb_acc[g * EMB + t], v);
    }
}

// ---------------- heads ----------------

__global__ __launch_bounds__(128) void k_head(const float* __restrict__ emb_acc,
                                              const int* __restrict__ gstart,
                                              const float* __restrict__ b2,
                                              const float* __restrict__ Wg,
                                              const float* __restrict__ bg,
                                              const float* __restrict__ Wf,
                                              const float* __restrict__ bff,
                                              float* __restrict__ out_emb,
                                              float* __restrict__ out_gl,
                                              float* __restrict__ out_fl) {
    __shared__ float e[EMB];
    __shared__ float gl[NGRP];
    __shared__ int ps;
    int g = blockIdx.x, c = threadIdx.x;
    bool nonempty = gstart[g + 1] > gstart[g];
    float a = emb_acc[g * EMB + c] + (nonempty ? b2[c] : 0.f);
    e[c] = a;
    out_emb[(size_t)g * EMB + c] = a;
    __syncthreads();
    if (c < NGRP) {
        float s = bg[c];
        for (int d = 0; d < EMB; ++d) s += e[d] * Wg[d * NGRP + c];
        gl[c] = s;
        out_gl[g * NGRP + c] = s;
    }
    __syncthreads();
    if (c == 0) {
        int bi = 0;
        float bv = gl[0];
        for (int t2 = 1; t2 < NGRP; ++t2)
            if (gl[t2] > bv) { bv = gl[t2]; bi = t2; }
        ps = bi;
    }
    __syncthreads();
    int pr = ps;
    float s = bff[pr * NFAM + c];
    for (int d = 0; d < EMB; ++d) s += e[d] * Wf[((size_t)pr * EMB + d) * NFAM + c];
    out_fl[g * NFAM + c] = s;
}

// ---------------- launch ----------------

extern "C" void kernel_launch(void* const* d_in, const int* in_sizes, int n_in,
                              void* d_out, int out_size, void* d_ws, size_t ws_size,
                              hipStream_t stream) {
    const float* x   = (const float*)d_in[0];
    const int*   ei  = (const int*)d_in[1];
    const int*   bat = (const int*)d_in[2];
    const float* W1  = (const float*)d_in[3];
    const float* b1  = (const float*)d_in[4];
    const float* W2  = (const float*)d_in[5];
    const float* b2  = (const float*)d_in[6];
    const float* Wg  = (const float*)d_in[7];
    const float* bg  = (const float*)d_in[8];
    const float* Wf  = (const float*)d_in[9];
    const float* bf  = (const float*)d_in[10];

    float* out     = (float*)d_out;
    float* out_emb = out;                        // 256*128
    float* out_gl  = out + (size_t)NG * EMB;     // 256*16
    float* out_fl  = out_gl + (size_t)NG * NGRP; // 256*128

    char* w = (char*)d_ws;
    auto alloc = [&](size_t bytes) {
        char* p = w;
        w += (bytes + 255) & ~(size_t)255;
        return p;
    };
    int*            degi    = (int*)alloc((size_t)NN * 4);
    float*          dinv    = (float*)alloc((size_t)NN * 4);
    int*            row_ptr = (int*)alloc((size_t)(NN + 1) * 4);
    int*            cursor  = (int*)alloc((size_t)NN * 4);
    int*            bsum    = (int*)alloc((size_t)SCAN_B * 4);
    uint32_t*       eP      = (uint32_t*)alloc((size_t)NETOT * 4);
    int*            gstart  = (int*)alloc((size_t)(NG + 1) * 4);
    float*          rcnt    = (float*)alloc((size_t)NG * 4);
    unsigned short* xs      = (unsigned short*)alloc((size_t)NN * FIN * 2);
    unsigned short* xa      = (unsigned short*)alloc((size_t)NN * FIN * 2);
    unsigned short* W1t     = (unsigned short*)alloc((size_t)HID * FIN * 2);
    unsigned short* W2t     = (unsigned short*)alloc((size_t)EMB * HID * 2);
    unsigned short* H       = (unsigned short*)alloc((size_t)NN * EMB * 2);
    float*          emb_acc = (float*)alloc((size_t)NG * EMB * 4);

    const int* esrc = ei;
    const int* edst = ei + NE;

    hipMemsetAsync(degi, 0, (size_t)NN * 4, stream);
    k_count<<<(NE + 255) / 256, 256, 0, stream>>>(edst, degi, NE);
    k_prep<<<(NG * HID + 255) / 256, 256, 0, stream>>>(degi, bat, dinv, gstart,
                                                       emb_acc, NN, NG);
    k_xconv<<<(NN * 16) / 256, 256, 0, stream>>>(x, dinv, xs);
    k_wconv<<<(HID * FIN + EMB * HID) / 256, 256, 0, stream>>>(W1, W2, W1t, W2t);
    k_scanA<<<SCAN_B, 256, 0, stream>>>(degi, row_ptr, bsum, NN);
    k_scanB<<<SCAN_B, 256, 0, stream>>>(bsum, gstart, rcnt, row_ptr, cursor, NN);
    k_build<<<NSLICE * BUILD_RANKS, 256, 0, stream>>>(esrc, edst, bat, dinv, rcnt,
                                                      row_ptr, cursor, eP, NN, NE);

    // layer 1 gather + fused (W1 -> relu -> W2, dinv_s folded) projection
    k_agg<<<(NN + 3) / 4, 256, 0, stream>>>(xs, row_ptr, eP, dinv, xa, NN);
    k_fgemm<<<(NN + 63) / 64, 256, 0, stream>>>(xa, W1t, W2t, b1, dinv, H, NN);

    // pool over graph-contiguous edges (128-feat rows)
    k_pool<<<NG * 8, 256, 0, stream>>>(H, row_ptr, gstart, eP, emb_acc);

    // heads
    k_head<<<NG, 128, 0, stream>>>(emb_acc, gstart, b2, Wg, bg, Wf, bf,
                                   out_emb, out_gl, out_fl);
}